// Round 5
// baseline (254.642 us; speedup 1.0000x reference)
//
#include <hip/hip_runtime.h>
#include <cmath>

#define Tn  2048
#define Cn  1024
#define Hn  64
#define BTn 16384

typedef _Float16 f16x8 __attribute__((ext_vector_type(8)));
typedef _Float16 f16x4 __attribute__((ext_vector_type(4)));
typedef _Float16 f16x2 __attribute__((ext_vector_type(2)));
typedef float    f32x4 __attribute__((ext_vector_type(4)));

#define MFMA16(a, b, c) __builtin_amdgcn_mfma_f32_16x16x32_f16(a, b, c, 0, 0, 0)

#define XSP 1032          // proj LDS row stride (f16): 516 dwords = 4 mod 32
#define PSP 72            // attn P-transpose row stride (f16)
#define SUBSZ 26368       // per-sub attn LDS: 9216 ps + 16640 ocomb + 512 mlcomb

// Device-scope software grid barrier. Grid is exactly co-resident
// (512 blocks x 2 blocks/CU x 256 CU), so spinning is safe. Epoch-based
// target makes it correct even if cnt starts at a stale multiple of
// gridDim (rocprof replay without the memset node). Bounded spin so a
// residency catastrophe fails loud instead of hanging the bench.
__device__ __forceinline__ void gbar(unsigned* cnt)
{
    __syncthreads();
    if (threadIdx.x == 0) {
        __threadfence();                               // release my writes
        unsigned prev   = atomicAdd(cnt, 1u);
        unsigned target = (prev / gridDim.x + 1u) * gridDim.x;
        for (int i = 0; i < (1 << 24); i++) {
            if (atomicAdd(cnt, 0u) >= target) break;   // device-scope read
            __builtin_amdgcn_s_sleep(1);
        }
        __threadfence();                               // acquire others'
    }
    __syncthreads();
}

// ---------------------------------------------------------------------------
// ONE kernel, three phases separated by software grid barriers:
//   phase 0 (blocks 0..47):  transpose Wq|Wk|Wv -> Wt[192][Cn] f16
//   phase 1 (all 512 blocks): qkv projection + RoPE (K-split 8-wave blocks,
//            3-slot rotating register prefetch; epilogue writes qh/kh and
//            vT[b][h][t])
//   phase 2: flash attention; each block = 2 virtual 256-thr attn blocks,
//            sub s handles (b = blk&7, qt = s ? 127-(blk>>3) : blk>>3) so
//            per-block causal work is constant.
// Rationale: wall - sum(kernel durs) was a CONSTANT ~68 us across rounds
// 0-3 (inter-dispatch overhead ~ both hot kernels combined). Fusing removes
// 2 of 3 launches. R4's hipLaunchCooperativeKernel never launched (output
// stayed zero); this version uses a plain launch + manual atomic barrier,
// which graph capture provably supports.
// ---------------------------------------------------------------------------
__global__ __launch_bounds__(512, 4) void fused_kernel(
    const float* __restrict__ x,  const float* __restrict__ Wq,
    const float* __restrict__ Wk, const float* __restrict__ Wv,
    _Float16* __restrict__ qh, _Float16* __restrict__ kh_g,
    _Float16* __restrict__ vT, _Float16* __restrict__ Wt,
    float* __restrict__ out, unsigned* __restrict__ cnt)
{
    __shared__ __align__(16) char smem[66048];   // 2 blocks/CU
    const int tid  = threadIdx.x;
    const int blk  = blockIdx.x;
    const int lane = tid & 63;
    const int quad = lane >> 4, l15 = lane & 15;

    // ------------------- phase 0: W transpose + f16 cast -------------------
    if (blk < 48) {                      // 48 = 3 proj * 16 c-tiles
        float (*ts)[65] = (float (*)[65])smem;
        const int p  = blk >> 4;
        const int c0 = (blk & 15) * 64;
        const float* __restrict__ W = (p == 0) ? Wq : (p == 1) ? Wk : Wv;
        #pragma unroll
        for (int it = 0; it < 8; it++) {
            int idx = tid + it * 512;
            int c = idx >> 6, n = idx & 63;
            ts[c][n] = W[(size_t)(c0 + c) * Hn + n];
        }
        __syncthreads();
        #pragma unroll
        for (int it = 0; it < 8; it++) {
            int idx = tid + it * 512;
            int n = idx >> 6, c = idx & 63;
            Wt[(size_t)(p * 64 + n) * Cn + c0 + c] = (_Float16)ts[c][n];
        }
    }
    gbar(cnt);

    // ------------------- phase 1: qkv projection + RoPE --------------------
    {
        _Float16* xs = (_Float16*)smem;
        const int row0  = blk * 32;
        const int wave  = tid >> 6;
        const int khalf = wave >> 2;     // K-half
        const int wc    = wave & 3;      // col group (48 cols)

        // Stage x (32 rows x 1024 fp32 -> f16). All 16 loads in flight.
        {
            float4 xv[16];
            #pragma unroll
            for (int it = 0; it < 16; it++) {
                int idx = tid + it * 512;
                int r = idx >> 8, c4 = idx & 255;
                xv[it] = *(const float4*)&x[(size_t)(row0 + r) * Cn + c4 * 4];
            }
            #pragma unroll
            for (int it = 0; it < 16; it++) {
                int idx = tid + it * 512;
                int r = idx >> 8, c4 = idx & 255;
                f16x4 hv = { (_Float16)xv[it].x, (_Float16)xv[it].y,
                             (_Float16)xv[it].z, (_Float16)xv[it].w };
                *(f16x4*)&xs[r * XSP + c4 * 4] = hv;
            }
        }
        __syncthreads();

        f32x4 acc[2][3] = {};
        const _Float16* __restrict__ wb = Wt + (size_t)(wc * 48 + l15) * Cn
                                             + khalf * 512 + quad * 8;
        const _Float16* __restrict__ xp = &xs[khalf * 512 + quad * 8];

        // 3-slot rotating prefetch over 16 kc steps (K-half = 512)
        f16x8 bb[3][3], ab[3][2];
        #pragma unroll
        for (int p = 0; p < 3; p++) {
            bb[p][0] = *(const f16x8*)&wb[p * 32];
            bb[p][1] = *(const f16x8*)&wb[16 * Cn + p * 32];
            bb[p][2] = *(const f16x8*)&wb[32 * Cn + p * 32];
            ab[p][0] = *(const f16x8*)&xp[(     l15) * XSP + p * 32];
            ab[p][1] = *(const f16x8*)&xp[(16 + l15) * XSP + p * 32];
        }
        #pragma unroll
        for (int kc = 0; kc < 16; kc++) {
            const int s = kc % 3;        // static after full unroll
            acc[0][0] = MFMA16(ab[s][0], bb[s][0], acc[0][0]);
            acc[1][0] = MFMA16(ab[s][1], bb[s][0], acc[1][0]);
            acc[0][1] = MFMA16(ab[s][0], bb[s][1], acc[0][1]);
            acc[1][1] = MFMA16(ab[s][1], bb[s][1], acc[1][1]);
            acc[0][2] = MFMA16(ab[s][0], bb[s][2], acc[0][2]);
            acc[1][2] = MFMA16(ab[s][1], bb[s][2], acc[1][2]);
            if (kc + 3 < 16) {
                const int kn = (kc + 3) * 32;
                bb[s][0] = *(const f16x8*)&wb[kn];
                bb[s][1] = *(const f16x8*)&wb[16 * Cn + kn];
                bb[s][2] = *(const f16x8*)&wb[32 * Cn + kn];
                ab[s][0] = *(const f16x8*)&xp[(     l15) * XSP + kn];
                ab[s][1] = *(const f16x8*)&xp[(16 + l15) * XSP + kn];
            }
        }

        // Combine K-halves through LDS (reuse xs)
        __syncthreads();
        f32x4* __restrict__ pbuf = (f32x4*)smem;    // 6*256*16B = 24.6 KB
        if (khalf) {
            #pragma unroll
            for (int mt = 0; mt < 2; mt++)
                #pragma unroll
                for (int nt = 0; nt < 3; nt++)
                    pbuf[(mt * 3 + nt) * 256 + wc * 64 + lane] = acc[mt][nt];
        }
        __syncthreads();
        if (!khalf) {
            #pragma unroll
            for (int mt = 0; mt < 2; mt++)
                #pragma unroll
                for (int nt = 0; nt < 3; nt++)
                    acc[mt][nt] += pbuf[(mt * 3 + nt) * 256 + wc * 64 + lane];

            // Epilogue (waves 0-3; wc owns cols [wc*48, wc*48+48))
            const int bidx = row0 >> 11;
            #pragma unroll
            for (int nt = 0; nt < 3; nt++) {
                const int n = wc * 48 + nt * 16 + l15;
                const int p = n >> 6;    // uniform per (wc,nt)
                const int h = n & 63;
                if (p < 2) {             // q or k: RoPE
                    _Float16* __restrict__ outb = (p == 0) ? qh : kh_g;
                    const float invf = __expf(-0.2878231366242557f * (float)(h >> 1));
                    #pragma unroll
                    for (int mt = 0; mt < 2; mt++) {
                        #pragma unroll
                        for (int r = 0; r < 4; r++) {
                            int   row = row0 + mt * 16 + quad * 4 + r;
                            float val = acc[mt][nt][r];
                            float partner = __shfl_xor(val, 1, 64);
                            float ang = (float)(row & (Tn - 1)) * invf;
                            float sv, cv;
                            __sincosf(ang, &sv, &cv);
                            float res = (h & 1) ? fmaf(val, cv,  partner * sv)
                                                : fmaf(val, cv, -partner * sv);
                            if (p == 0) res *= 0.125f;
                            float resn = __shfl_xor(res, 1, 64);
                            if (!(l15 & 1)) {
                                f16x2 pk = { (_Float16)res, (_Float16)resn };
                                *(f16x2*)&outb[(size_t)row * Hn + h] = pk;
                            }
                        }
                    }
                } else {                 // v: store transposed vT[b][h][t]
                    #pragma unroll
                    for (int mt = 0; mt < 2; mt++) {
                        int t = (row0 & (Tn - 1)) + mt * 16 + quad * 4;
                        f16x4 pv = { (_Float16)acc[mt][nt][0], (_Float16)acc[mt][nt][1],
                                     (_Float16)acc[mt][nt][2], (_Float16)acc[mt][nt][3] };
                        *(f16x4*)&vT[((size_t)bidx * Hn + h) * Tn + t] = pv;
                    }
                }
            }
        }
    }
    gbar(cnt);

    // ------------------- phase 2: flash attention --------------------------
    {
        const int sub  = tid >> 8;       // virtual 256-thr attn block
        const int stid = tid & 255;
        const int w    = stid >> 6;
        const int m    = blk >> 3;       // 0..63
        const int b    = blk & 7;        // batch == XCD affinity
        const int qt   = sub ? (127 - m) : m;   // per-block work = const
        const int t0   = qt * 16;

        _Float16* ps  = (_Float16*)(smem + sub * SUBSZ);               // [4][16*PSP]
        float*    ocm = (float*)  (smem + sub * SUBSZ + 9216);         // [4][16][65]
        float*    mlc = (float*)  (smem + sub * SUBSZ + 9216 + 16640); // [4][2][16]

        const _Float16* __restrict__ qb = qh   + (size_t)b * Tn * Hn;
        const _Float16* __restrict__ kb = kh_g + (size_t)b * Tn * Hn;
        const _Float16* __restrict__ vb = vT   + (size_t)b * Hn * Tn;

        // Q A-frags: held in registers for the whole loop
        const f16x8 aq0 = *(const f16x8*)&qb[(size_t)(t0 + l15) * Hn +      quad * 8];
        const f16x8 aq1 = *(const f16x8*)&qb[(size_t)(t0 + l15) * Hn + 32 + quad * 8];

        float m_run[4], l_run[4];
        f32x4 oacc[4] = {};
        #pragma unroll
        for (int r = 0; r < 4; r++) { m_run[r] = -1e30f; l_run[r] = 0.0f; }

        const int nst = (t0 + 16 + 63) >> 6;
        for (int jt = w; jt < nst; jt += 4) {
            const int s0 = jt * 64;

            // K B-frags direct from global (16 rows x 64B per load instr)
            f16x8 kf[4][2];
            #pragma unroll
            for (int nt = 0; nt < 4; nt++) {
                const _Float16* kp = &kb[(size_t)(s0 + nt * 16 + l15) * Hn + quad * 8];
                kf[nt][0] = *(const f16x8*)kp;
                kf[nt][1] = *(const f16x8*)(kp + 32);
            }
            f32x4 sacc[4];
            #pragma unroll
            for (int nt = 0; nt < 4; nt++) {
                f32x4 z = {};
                z = MFMA16(aq0, kf[nt][0], z);
                z = MFMA16(aq1, kf[nt][1], z);
                sacc[nt] = z;
            }

            // vT B-frags: issue before softmax (independent), consumed by PV
            f16x8 vf[2][4];
            #pragma unroll
            for (int sc = 0; sc < 2; sc++)
                #pragma unroll
                for (int ht = 0; ht < 4; ht++)
                    vf[sc][ht] = *(const f16x8*)&vb[(size_t)(ht * 16 + l15) * Tn
                                                    + s0 + sc * 32 + quad * 8];

            if (jt == nst - 1) {         // causal mask: only diagonal tile
                #pragma unroll
                for (int nt = 0; nt < 4; nt++)
                    #pragma unroll
                    for (int r = 0; r < 4; r++) {
                        int scol = s0 + nt * 16 + l15;
                        int trow = t0 + quad * 4 + r;
                        if (scol > trow) sacc[nt][r] = -1e30f;
                    }
            }

            // online softmax (rows = quad*4+r; reduce over the 16 l15 lanes)
            float pr[4][4];
            #pragma unroll
            for (int r = 0; r < 4; r++) {
                float mx = fmaxf(fmaxf(sacc[0][r], sacc[1][r]),
                                 fmaxf(sacc[2][r], sacc[3][r]));
                #pragma unroll
                for (int off = 1; off < 16; off <<= 1)
                    mx = fmaxf(mx, __shfl_xor(mx, off, 64));
                float mnew  = fmaxf(m_run[r], mx);
                float alpha = __expf(m_run[r] - mnew);
                m_run[r] = mnew;
                float rs = 0.0f;
                #pragma unroll
                for (int nt = 0; nt < 4; nt++) {
                    float pv = __expf(sacc[nt][r] - mnew);
                    pr[nt][r] = pv; rs += pv;
                }
                #pragma unroll
                for (int off = 1; off < 16; off <<= 1)
                    rs += __shfl_xor(rs, off, 64);
                l_run[r] = fmaf(l_run[r], alpha, rs);
                #pragma unroll
                for (int ht = 0; ht < 4; ht++)
                    oacc[ht][r] = oacc[ht][r] * alpha;
            }

            // P -> ps (wave-private; same-wave RAW, no barrier)
            #pragma unroll
            for (int nt = 0; nt < 4; nt++)
                #pragma unroll
                for (int r = 0; r < 4; r++) {
                    float pv = pr[nt][r];
                    float pn = __shfl_xor(pv, 1, 64);
                    if (!(l15 & 1)) {
                        f16x2 pk = { (_Float16)pv, (_Float16)pn };
                        *(f16x2*)&ps[w * 16 * PSP + (quad * 4 + r) * PSP + nt * 16 + l15] = pk;
                    }
                }

            // O += P V  (8 MFMA, B-frags already in registers)
            #pragma unroll
            for (int sc = 0; sc < 2; sc++) {
                f16x8 ap = *(const f16x8*)&ps[w * 16 * PSP + l15 * PSP + sc * 32 + quad * 8];
                #pragma unroll
                for (int ht = 0; ht < 4; ht++)
                    oacc[ht] = MFMA16(ap, vf[sc][ht], oacc[ht]);
            }
        }

        // Write partials, barrier, merge the four waves' softmax states.
        #pragma unroll
        for (int r = 0; r < 4; r++) {
            #pragma unroll
            for (int ht = 0; ht < 4; ht++)
                ocm[(w * 16 + quad * 4 + r) * 65 + ht * 16 + l15] = oacc[ht][r];
            if (l15 == 0) {
                mlc[(w * 2 + 0) * 16 + quad * 4 + r] = m_run[r];
                mlc[(w * 2 + 1) * 16 + quad * 4 + r] = l_run[r];
            }
        }
        __syncthreads();                 // syncs both subs; regions disjoint

        // wave w finalizes rows [w*4, w*4+4); 64 lanes = 64 h (coalesced)
        #pragma unroll
        for (int rp = 0; rp < 4; rp++) {
            int row = w * 4 + rp;
            float m0 = mlc[(0) * 16 + row], m1 = mlc[(2) * 16 + row];
            float m2 = mlc[(4) * 16 + row], m3 = mlc[(6) * 16 + row];
            float mm = fmaxf(fmaxf(m0, m1), fmaxf(m2, m3));
            float a0 = __expf(m0 - mm), a1 = __expf(m1 - mm);
            float a2 = __expf(m2 - mm), a3 = __expf(m3 - mm);
            float ll = mlc[(1) * 16 + row] * a0 + mlc[(3) * 16 + row] * a1
                     + mlc[(5) * 16 + row] * a2 + mlc[(7) * 16 + row] * a3;
            float ov = (ocm[(0 * 16 + row) * 65 + lane] * a0
                      + ocm[(1 * 16 + row) * 65 + lane] * a1
                      + ocm[(2 * 16 + row) * 65 + lane] * a2
                      + ocm[(3 * 16 + row) * 65 + lane] * a3) / ll;
            out[((size_t)b * Tn + t0 + row) * Hn + lane] = ov;
        }
    }
}

extern "C" void kernel_launch(void* const* d_in, const int* in_sizes, int n_in,
                              void* d_out, int out_size, void* d_ws, size_t ws_size,
                              hipStream_t stream) {
    const float* x  = (const float*)d_in[0];
    const float* Wq = (const float*)d_in[1];
    const float* Wk = (const float*)d_in[2];
    const float* Wv = (const float*)d_in[3];

    const size_t qkvN = (size_t)BTn * Hn;
    _Float16* qh = (_Float16*)d_ws;
    _Float16* kh = qh + qkvN;
    _Float16* vT = kh + qkvN;                     // [8][64][2048] transposed
    _Float16* Wt = vT + qkvN;                     // [192][1024] f16
    unsigned* cnt = (unsigned*)(Wt + (size_t)192 * Cn);   // barrier counter
    float*    op  = (float*)d_out;

    hipMemsetAsync(cnt, 0, 128, stream);          // reset barrier each launch
    hipLaunchKernelGGL(fused_kernel, dim3(512), dim3(512), 0, stream,
                       x, Wq, Wk, Wv, qh, kh, vT, Wt, op, cnt);
}

// Round 6
// 156.458 us; speedup vs baseline: 1.6275x; 1.6275x over previous
//
#include <hip/hip_runtime.h>
#include <cmath>

#define Tn  2048
#define Cn  1024
#define Hn  64
#define BTn 16384

typedef _Float16 f16x8 __attribute__((ext_vector_type(8)));
typedef _Float16 f16x4 __attribute__((ext_vector_type(4)));
typedef _Float16 f16x2 __attribute__((ext_vector_type(2)));
typedef float    f32x4 __attribute__((ext_vector_type(4)));

#define MFMA16(a, b, c) __builtin_amdgcn_mfma_f32_16x16x32_f16(a, b, c, 0, 0, 0)

// async global->LDS, 16B per lane, wave-uniform LDS base (HW adds lane*16)
__device__ __forceinline__ void gload16(const void* g, void* l) {
    __builtin_amdgcn_global_load_lds(
        (const __attribute__((address_space(1))) void*)g,
        (__attribute__((address_space(3))) void*)l, 16, 0, 0);
}

// ---------------------------------------------------------------------------
// prep: transpose Wq|Wk|Wv (each [Cn][64] fp32) into Wt[192][Cn] f16
// ---------------------------------------------------------------------------
__global__ __launch_bounds__(256) void prep_w_kernel(
    const float* __restrict__ Wq, const float* __restrict__ Wk,
    const float* __restrict__ Wv, _Float16* __restrict__ Wt)
{
    __shared__ float ts[64][65];
    const int blk = blockIdx.x;          // 48 = 3 proj * 16 c-tiles
    const int p   = blk >> 4;
    const int c0  = (blk & 15) * 64;
    const float* __restrict__ W = (p == 0) ? Wq : (p == 1) ? Wk : Wv;
    const int tid = threadIdx.x;
    #pragma unroll
    for (int it = 0; it < 16; it++) {
        int idx = tid + it * 256;
        int c = idx >> 6, n = idx & 63;
        ts[c][n] = W[(size_t)(c0 + c) * Hn + n];
    }
    __syncthreads();
    #pragma unroll
    for (int it = 0; it < 16; it++) {
        int idx = tid + it * 256;
        int n = idx >> 6, c = idx & 63;
        Wt[(size_t)(p * 64 + n) * Cn + c0 + c] = (_Float16)ts[c][n];
    }
}

// ---------------------------------------------------------------------------
// proj, round-6 structure. Diagnosis: FETCH 34 MB / 900 GB/s = 38 us == the
// kernel time; staging flight depth (~1 KB/CU at VGPR 52) capped HBM at 14%.
// Fix: stage x via global_load_lds (no VGPR round trip; queue stays deep:
// ~128 KB/CU in flight >> the ~9 KB needed to cover HBM latency).
// Consequence: x lands in LDS as RAW FP32 -> stage K in two 64 KB halves
// ([32][512] f32, linear layout for the DMA, 2 blocks/CU preserved), and
// convert fp32->f16 with 8 scalar casts at A-frag build (VALU co-issues
// with MFMA, m114). Stride 2048 B would be a 16-way bank conflict, so the
// GLOBAL SOURCE address is pre-swizzled with byte ^= (row&7)<<4 and the
// ds_read applies the same XOR (both-sides rule; LDS dest stays linear).
// Wave = (kh, wc): kh = K-quarter within the staged half, wc = col group
// of 48; acc[2][3] per wave; Wt read once per block (192 MB L2 total);
// 2-partial combine through LDS; epilogue (RoPE, vT transpose) unchanged.
// ---------------------------------------------------------------------------
__device__ __forceinline__ f16x8 ldsA(const char* xb, int row, int col) {
    int lb = row * 2048 + col * 4;       // linear byte offset, 16B aligned
    int sw = (row & 7) << 4;             // swizzle (matches staged source)
    f32x4 lo = *(const f32x4*)(xb + ((lb     ) ^ sw));
    f32x4 hi = *(const f32x4*)(xb + ((lb + 16) ^ sw));
    f16x8 r;
    r[0] = (_Float16)lo[0]; r[1] = (_Float16)lo[1];
    r[2] = (_Float16)lo[2]; r[3] = (_Float16)lo[3];
    r[4] = (_Float16)hi[0]; r[5] = (_Float16)hi[1];
    r[6] = (_Float16)hi[2]; r[7] = (_Float16)hi[3];
    return r;
}

__global__ __launch_bounds__(512, 4) void proj_kernel(
    const float* __restrict__ x, const _Float16* __restrict__ Wt,
    _Float16* __restrict__ qh, _Float16* __restrict__ kh_out, _Float16* __restrict__ vT)
{
    __shared__ __align__(16) float xsf[32 * 512];   // 64 KB -> 2 blocks/CU
    const int row0 = blockIdx.x * 32;
    const int tid  = threadIdx.x;
    const int wave = tid >> 6, lane = tid & 63;
    const int kh   = wave >> 2;          // K-quarter within staged half
    const int wc   = wave & 3;           // col group (48 cols)
    const int quad = lane >> 4, l15 = lane & 15;

    f32x4 acc[2][3] = {};
    const _Float16* __restrict__ wb = Wt + (size_t)(wc * 48 + l15) * Cn + quad * 8;
    const char* xb = (const char*)xsf;

    #pragma unroll
    for (int ph = 0; ph < 2; ph++) {
        if (ph) __syncthreads();         // all waves done reading half 0

        // Stage 32 rows x 512 fp32 = 64 KB via global_load_lds (8 issues
        // per thread, all in flight; LDS dest linear, source pre-swizzled).
        {
            const char* xg = (const char*)x + ((size_t)row0 * Cn + ph * 512) * 4;
            char* lb0 = (char*)xsf + wave * 1024;    // wave-uniform base
            #pragma unroll
            for (int r2 = 0; r2 < 8; r2++) {
                int lbl  = tid * 16 + r2 * 8192;     // this lane's dest byte
                int row  = lbl >> 11;
                int colb = (lbl & 2047) ^ ((row & 7) << 4);
                gload16(xg + (size_t)row * (Cn * 4) + colb, lb0 + r2 * 8192);
            }
        }
        __syncthreads();                 // vmcnt(0) drain + barrier

        // K-quarter [kh*256, kh*256+256) of this half: 8 kc steps of 32
        #pragma unroll
        for (int kc = 0; kc < 8; kc++) {
            const int kf = kh * 256 + kc * 32;       // f32 idx in half
            f16x8 b0 = *(const f16x8*)&wb[ph * 512 + kf];
            f16x8 b1 = *(const f16x8*)&wb[16 * Cn + ph * 512 + kf];
            f16x8 b2 = *(const f16x8*)&wb[32 * Cn + ph * 512 + kf];
            f16x8 a0 = ldsA(xb,      l15, kf + quad * 8);
            f16x8 a1 = ldsA(xb, 16 + l15, kf + quad * 8);
            acc[0][0] = MFMA16(a0, b0, acc[0][0]);
            acc[1][0] = MFMA16(a1, b0, acc[1][0]);
            acc[0][1] = MFMA16(a0, b1, acc[0][1]);
            acc[1][1] = MFMA16(a1, b1, acc[1][1]);
            acc[0][2] = MFMA16(a0, b2, acc[0][2]);
            acc[1][2] = MFMA16(a1, b2, acc[1][2]);
        }
    }

    // Combine the two K-quarter groups: waves kh=1 dump partials into LDS
    // (reuse xsf), waves kh=0 add them. Lane-major f32x4 = conflict-free.
    __syncthreads();                     // everyone done reading xsf
    f32x4* __restrict__ pbuf = (f32x4*)xsf;     // 6*256*16B = 24.6 KB
    if (kh) {
        #pragma unroll
        for (int mt = 0; mt < 2; mt++)
            #pragma unroll
            for (int nt = 0; nt < 3; nt++)
                pbuf[(mt * 3 + nt) * 256 + wc * 64 + lane] = acc[mt][nt];
    }
    __syncthreads();
    if (kh) return;
    #pragma unroll
    for (int mt = 0; mt < 2; mt++)
        #pragma unroll
        for (int nt = 0; nt < 3; nt++)
            acc[mt][nt] += pbuf[(mt * 3 + nt) * 256 + wc * 64 + lane];

    // Epilogue (waves 0-3; wc owns cols [wc*48, wc*48+48))
    const int bidx = row0 >> 11;
    #pragma unroll
    for (int nt = 0; nt < 3; nt++) {
        const int n = wc * 48 + nt * 16 + l15;
        const int p = n >> 6;            // uniform per (wc,nt)
        const int h = n & 63;
        if (p < 2) {                     // q or k: RoPE
            _Float16* __restrict__ outb = (p == 0) ? qh : kh_out;
            const float invf = __expf(-0.2878231366242557f * (float)(h >> 1));
            #pragma unroll
            for (int mt = 0; mt < 2; mt++) {
                #pragma unroll
                for (int r = 0; r < 4; r++) {
                    int   row = row0 + mt * 16 + quad * 4 + r;
                    float val = acc[mt][nt][r];
                    float partner = __shfl_xor(val, 1, 64);
                    float ang = (float)(row & (Tn - 1)) * invf;
                    float sv, cv;
                    __sincosf(ang, &sv, &cv);
                    float res = (h & 1) ? fmaf(val, cv,  partner * sv)
                                        : fmaf(val, cv, -partner * sv);
                    if (p == 0) res *= 0.125f;
                    float resn = __shfl_xor(res, 1, 64);
                    if (!(l15 & 1)) {
                        f16x2 pk = { (_Float16)res, (_Float16)resn };
                        *(f16x2*)&outb[(size_t)row * Hn + h] = pk;
                    }
                }
            }
        } else {                         // v: store transposed vT[b][h][t]
            #pragma unroll
            for (int mt = 0; mt < 2; mt++) {
                int t = (row0 & (Tn - 1)) + mt * 16 + quad * 4;
                f16x4 pv = { (_Float16)acc[mt][nt][0], (_Float16)acc[mt][nt][1],
                             (_Float16)acc[mt][nt][2], (_Float16)acc[mt][nt][3] };
                *(f16x4*)&vT[((size_t)bidx * Hn + h) * Tn + t] = pv;
            }
        }
    }
}

// ---------------------------------------------------------------------------
// attn: barrier-free flash loop (EXACT round-2 version, the best measured).
// QT=16, STL=64, 256 thr = 4 waves; each wave processes every 4th s-tile
// with its own online-softmax state; one barrier + LDS merge at the end.
// K and vT B-frags read directly from global (L2-resident, XCD-affine via
// b = blk&7). qt permuted so each CU's resident blocks have constant work.
// ---------------------------------------------------------------------------
#define PSP 72

__global__ __launch_bounds__(256, 4) void attn_kernel(
    const _Float16* __restrict__ qh, const _Float16* __restrict__ kh,
    const _Float16* __restrict__ vT, float* __restrict__ out)
{
    __shared__ _Float16 ps[4][16 * PSP];     // wave-private P transpose
    __shared__ float ocomb[4][16][65];
    __shared__ float mlcomb[4][2][16];       // [wave][m|l][row]

    const int blk = blockIdx.x;
    const int b   = blk & 7;                 // batch == XCD affinity
    const int j   = blk >> 3;                // 0..127
    const int jm  = j & 31, g = j >> 5;      // complement permutation:
    const int qt  = (g == 0) ? (127 - jm)    // per-CU resident set sums const
                  : (g == 1) ? (64 + jm)
                  : (g == 2) ? (63 - jm) : jm;
    const int t0  = qt * 16;
    const int tid = threadIdx.x;
    const int w = tid >> 6, lane = tid & 63;
    const int quad = lane >> 4, l15 = lane & 15;

    const _Float16* __restrict__ qb = qh + (size_t)b * Tn * Hn;
    const _Float16* __restrict__ kb = kh + (size_t)b * Tn * Hn;
    const _Float16* __restrict__ vb = vT + (size_t)b * Hn * Tn;

    // Q A-frags: held in registers for the whole loop
    const f16x8 aq0 = *(const f16x8*)&qb[(size_t)(t0 + l15) * Hn +      quad * 8];
    const f16x8 aq1 = *(const f16x8*)&qb[(size_t)(t0 + l15) * Hn + 32 + quad * 8];

    float m_run[4], l_run[4];
    f32x4 oacc[4] = {};
    #pragma unroll
    for (int r = 0; r < 4; r++) { m_run[r] = -1e30f; l_run[r] = 0.0f; }

    const int nst = (t0 + 16 + 63) >> 6;
    for (int jt = w; jt < nst; jt += 4) {
        const int s0 = jt * 64;

        // K B-frags direct from global (16 rows x 64B per load instr)
        f16x8 kf[4][2];
        #pragma unroll
        for (int nt = 0; nt < 4; nt++) {
            const _Float16* kp = &kb[(size_t)(s0 + nt * 16 + l15) * Hn + quad * 8];
            kf[nt][0] = *(const f16x8*)kp;
            kf[nt][1] = *(const f16x8*)(kp + 32);
        }
        f32x4 sacc[4];
        #pragma unroll
        for (int nt = 0; nt < 4; nt++) {
            f32x4 z = {};
            z = MFMA16(aq0, kf[nt][0], z);
            z = MFMA16(aq1, kf[nt][1], z);
            sacc[nt] = z;
        }

        // vT B-frags: issue before softmax (independent), consumed by PV
        f16x8 vf[2][4];
        #pragma unroll
        for (int sc = 0; sc < 2; sc++)
            #pragma unroll
            for (int ht = 0; ht < 4; ht++)
                vf[sc][ht] = *(const f16x8*)&vb[(size_t)(ht * 16 + l15) * Tn
                                                + s0 + sc * 32 + quad * 8];

        if (jt == nst - 1) {             // causal mask: only diagonal tile
            #pragma unroll
            for (int nt = 0; nt < 4; nt++)
                #pragma unroll
                for (int r = 0; r < 4; r++) {
                    int scol = s0 + nt * 16 + l15;
                    int trow = t0 + quad * 4 + r;
                    if (scol > trow) sacc[nt][r] = -1e30f;
                }
        }

        // online softmax (rows = quad*4+r; reduce over the 16 l15 lanes)
        float pr[4][4];
        #pragma unroll
        for (int r = 0; r < 4; r++) {
            float mx = fmaxf(fmaxf(sacc[0][r], sacc[1][r]),
                             fmaxf(sacc[2][r], sacc[3][r]));
            #pragma unroll
            for (int off = 1; off < 16; off <<= 1)
                mx = fmaxf(mx, __shfl_xor(mx, off, 64));
            float mnew  = fmaxf(m_run[r], mx);
            float alpha = __expf(m_run[r] - mnew);
            m_run[r] = mnew;
            float rs = 0.0f;
            #pragma unroll
            for (int nt = 0; nt < 4; nt++) {
                float pv = __expf(sacc[nt][r] - mnew);
                pr[nt][r] = pv; rs += pv;
            }
            #pragma unroll
            for (int off = 1; off < 16; off <<= 1)
                rs += __shfl_xor(rs, off, 64);
            l_run[r] = fmaf(l_run[r], alpha, rs);
            #pragma unroll
            for (int ht = 0; ht < 4; ht++)
                oacc[ht][r] = oacc[ht][r] * alpha;
        }

        // P -> ps (wave-private; same-wave RAW, no barrier)
        #pragma unroll
        for (int nt = 0; nt < 4; nt++)
            #pragma unroll
            for (int r = 0; r < 4; r++) {
                float pv = pr[nt][r];
                float pn = __shfl_xor(pv, 1, 64);
                if (!(l15 & 1)) {
                    f16x2 pk = { (_Float16)pv, (_Float16)pn };
                    *(f16x2*)&ps[w][(quad * 4 + r) * PSP + nt * 16 + l15] = pk;
                }
            }

        // O += P V  (8 MFMA, B-frags already in registers)
        #pragma unroll
        for (int sc = 0; sc < 2; sc++) {
            f16x8 ap = *(const f16x8*)&ps[w][l15 * PSP + sc * 32 + quad * 8];
            #pragma unroll
            for (int ht = 0; ht < 4; ht++)
                oacc[ht] = MFMA16(ap, vf[sc][ht], oacc[ht]);
        }
    }

    // Write partials, barrier, merge the four waves' online-softmax states.
    #pragma unroll
    for (int r = 0; r < 4; r++) {
        #pragma unroll
        for (int ht = 0; ht < 4; ht++)
            ocomb[w][quad * 4 + r][ht * 16 + l15] = oacc[ht][r];
        if (l15 == 0) {
            mlcomb[w][0][quad * 4 + r] = m_run[r];
            mlcomb[w][1][quad * 4 + r] = l_run[r];
        }
    }
    __syncthreads();

    // wave w finalizes rows [w*4, w*4+4); 64 lanes = 64 h (coalesced)
    #pragma unroll
    for (int rp = 0; rp < 4; rp++) {
        int row = w * 4 + rp;
        float m0 = mlcomb[0][0][row], m1 = mlcomb[1][0][row];
        float m2 = mlcomb[2][0][row], m3 = mlcomb[3][0][row];
        float mm = fmaxf(fmaxf(m0, m1), fmaxf(m2, m3));
        float a0 = __expf(m0 - mm), a1 = __expf(m1 - mm);
        float a2 = __expf(m2 - mm), a3 = __expf(m3 - mm);
        float ll = mlcomb[0][1][row] * a0 + mlcomb[1][1][row] * a1
                 + mlcomb[2][1][row] * a2 + mlcomb[3][1][row] * a3;
        float ov = (ocomb[0][row][lane] * a0 + ocomb[1][row][lane] * a1
                  + ocomb[2][row][lane] * a2 + ocomb[3][row][lane] * a3) / ll;
        out[((size_t)b * Tn + t0 + row) * Hn + lane] = ov;
    }
}

extern "C" void kernel_launch(void* const* d_in, const int* in_sizes, int n_in,
                              void* d_out, int out_size, void* d_ws, size_t ws_size,
                              hipStream_t stream) {
    const float* x  = (const float*)d_in[0];
    const float* Wq = (const float*)d_in[1];
    const float* Wk = (const float*)d_in[2];
    const float* Wv = (const float*)d_in[3];

    const size_t qkvN = (size_t)BTn * Hn;
    _Float16* qh = (_Float16*)d_ws;
    _Float16* kh = qh + qkvN;
    _Float16* vT = kh + qkvN;                     // [8][64][2048] transposed
    _Float16* Wt = vT + qkvN;                     // [192][1024] f16

    prep_w_kernel<<<48, 256, 0, stream>>>(Wq, Wk, Wv, Wt);
    proj_kernel<<<BTn / 32, 512, 0, stream>>>(x, Wt, qh, kh, vT);
    attn_kernel<<<1024, 256, 0, stream>>>(qh, kh, vT, (float*)d_out);
}

// Round 7
// 154.708 us; speedup vs baseline: 1.6460x; 1.0113x over previous
//
#include <hip/hip_runtime.h>
#include <cmath>

#define Tn  2048
#define Cn  1024
#define Hn  64
#define BTn 16384

typedef _Float16 f16x8 __attribute__((ext_vector_type(8)));
typedef _Float16 f16x4 __attribute__((ext_vector_type(4)));
typedef _Float16 f16x2 __attribute__((ext_vector_type(2)));
typedef float    f32x4 __attribute__((ext_vector_type(4)));

#define MFMA16(a, b, c) __builtin_amdgcn_mfma_f32_16x16x32_f16(a, b, c, 0, 0, 0)

// async global->LDS, 16B per lane, wave-uniform LDS base (HW adds lane*16)
__device__ __forceinline__ void gload16(const void* g, void* l) {
    __builtin_amdgcn_global_load_lds(
        (const __attribute__((address_space(1))) void*)g,
        (__attribute__((address_space(3))) void*)l, 16, 0, 0);
}

// ---------------------------------------------------------------------------
// prep: transpose Wq|Wk|Wv (each [Cn][64] fp32) into Wt[192][Cn] f16
// ---------------------------------------------------------------------------
__global__ __launch_bounds__(256) void prep_w_kernel(
    const float* __restrict__ Wq, const float* __restrict__ Wk,
    const float* __restrict__ Wv, _Float16* __restrict__ Wt)
{
    __shared__ float ts[64][65];
    const int blk = blockIdx.x;          // 48 = 3 proj * 16 c-tiles
    const int p   = blk >> 4;
    const int c0  = (blk & 15) * 64;
    const float* __restrict__ W = (p == 0) ? Wq : (p == 1) ? Wk : Wv;
    const int tid = threadIdx.x;
    #pragma unroll
    for (int it = 0; it < 16; it++) {
        int idx = tid + it * 256;
        int c = idx >> 6, n = idx & 63;
        ts[c][n] = W[(size_t)(c0 + c) * Hn + n];
    }
    __syncthreads();
    #pragma unroll
    for (int it = 0; it < 16; it++) {
        int idx = tid + it * 256;
        int n = idx >> 6, c = idx & 63;
        Wt[(size_t)(p * 64 + n) * Cn + c0 + c] = (_Float16)ts[c][n];
    }
}

// ---------------------------------------------------------------------------
// proj, round-7: double-buffered staging with FIFO-safe issue order.
// R6 showed stage and compute strictly serialize (barrier drains vmcnt(0)
// while all waves wait): HBM stuck at 900 GB/s, MfmaUtil 5%. Now K is split
// into 4 phases of 256 f32; two 32 KB LDS buffers alternate (64 KB total,
// 2 blocks/CU kept). Per phase, IN THIS ORDER:
//   1. 12 Wt B-frags -> registers      (oldest in the vmcnt FIFO)
//   2. sched_barrier; issue next phase's global_load_lds; sched_barrier
//   3. compute 4 kc (ds_read + cvt + MFMA)  -- compiler waits for Wt uses
//      count only OLDER loads, so the stage stays in flight under compute
//   4. __syncthreads (its vmcnt(0) collects the stage after ~1 us of cover)
// vmcnt retires in issue order (m135), so Wt-before-stage is what keeps the
// stage un-drained. WAR on the shared buffer is safe: reads of buf[(p-1)&1]
// completed at the previous barrier (lgkmcnt(0)).
// x lands as RAW FP32; fp32->f16 casts fold into A-frag build (VALU
// co-issues with MFMA, m114). Bank swizzle: global SOURCE pre-swizzled
// byte ^= (row&7)<<4, ds_read applies the same XOR (both-sides rule,
// LDS dest linear). Wave = (kh, wc): kh = K-half of the phase, wc = col
// group of 48; acc[2][3]; partials combined via LDS; epilogue (RoPE, vT
// transpose) unchanged.
// ---------------------------------------------------------------------------
__device__ __forceinline__ f16x8 ldsA(const char* xb, int row, int col) {
    int lb = row * 1024 + col * 4;       // linear byte offset, 16B aligned
    int sw = (row & 7) << 4;             // swizzle (matches staged source)
    f32x4 lo = *(const f32x4*)(xb + ((lb     ) ^ sw));
    f32x4 hi = *(const f32x4*)(xb + ((lb + 16) ^ sw));
    f16x8 r;
    r[0] = (_Float16)lo[0]; r[1] = (_Float16)lo[1];
    r[2] = (_Float16)lo[2]; r[3] = (_Float16)lo[3];
    r[4] = (_Float16)hi[0]; r[5] = (_Float16)hi[1];
    r[6] = (_Float16)hi[2]; r[7] = (_Float16)hi[3];
    return r;
}

__global__ __launch_bounds__(512, 4) void proj_kernel(
    const float* __restrict__ x, const _Float16* __restrict__ Wt,
    _Float16* __restrict__ qh, _Float16* __restrict__ kh_out, _Float16* __restrict__ vT)
{
    __shared__ __align__(16) float xsf[2][32 * 256];   // 2 x 32 KB -> 2 blk/CU
    const int row0 = blockIdx.x * 32;
    const int tid  = threadIdx.x;
    const int wave = tid >> 6, lane = tid & 63;
    const int kh   = wave >> 2;          // K-half within the staged phase
    const int wc   = wave & 3;           // col group (48 cols)
    const int quad = lane >> 4, l15 = lane & 15;

    f32x4 acc[2][3] = {};
    const _Float16* __restrict__ wb = Wt + (size_t)(wc * 48 + l15) * Cn + quad * 8;

    // stage phase p (32 rows x 256 f32 = 32 KB) into buf[p&1]; each wave
    // writes whole rows (row = wave + r2*8, uniform per wave per issue),
    // source pre-swizzled so the linear-dest DMA lands bank-spread data.
    #define STAGE(p)                                                          \
    {                                                                         \
        const char* xg = (const char*)(x + (size_t)row0 * Cn + (p) * 256);    \
        char* lb0 = (char*)xsf[(p) & 1] + wave * 1024;                        \
        _Pragma("unroll")                                                     \
        for (int r2 = 0; r2 < 4; r2++) {                                      \
            int row  = wave + r2 * 8;                                         \
            int colb = (lane * 16) ^ ((row & 7) << 4);                        \
            gload16(xg + (size_t)row * (Cn * 4) + colb, lb0 + r2 * 8192);     \
        }                                                                     \
    }

    STAGE(0);
    __syncthreads();                     // vmcnt(0): buf0 ready

    #pragma unroll
    for (int p = 0; p < 4; p++) {
        // 1) Wt B-frags for this phase -> registers (oldest in FIFO)
        f16x8 wt[4][3];
        #pragma unroll
        for (int kc = 0; kc < 4; kc++) {
            const int kf = p * 256 + kh * 128 + kc * 32;
            wt[kc][0] = *(const f16x8*)&wb[kf];
            wt[kc][1] = *(const f16x8*)&wb[16 * Cn + kf];
            wt[kc][2] = *(const f16x8*)&wb[32 * Cn + kf];
        }
        __builtin_amdgcn_sched_barrier(0);
        // 2) issue next stage (stays in flight under the whole compute)
        if (p < 3) STAGE(p + 1);
        __builtin_amdgcn_sched_barrier(0);
        // 3) compute this phase from buf[p&1]
        const char* xb = (const char*)xsf[p & 1];
        #pragma unroll
        for (int kc = 0; kc < 4; kc++) {
            const int cf = kh * 128 + kc * 32 + quad * 8;
            f16x8 a0 = ldsA(xb,      l15, cf);
            f16x8 a1 = ldsA(xb, 16 + l15, cf);
            acc[0][0] = MFMA16(a0, wt[kc][0], acc[0][0]);
            acc[1][0] = MFMA16(a1, wt[kc][0], acc[1][0]);
            acc[0][1] = MFMA16(a0, wt[kc][1], acc[0][1]);
            acc[1][1] = MFMA16(a1, wt[kc][1], acc[1][1]);
            acc[0][2] = MFMA16(a0, wt[kc][2], acc[0][2]);
            acc[1][2] = MFMA16(a1, wt[kc][2], acc[1][2]);
        }
        // 4) barrier: drains the in-flight stage (covered by compute above)
        __syncthreads();
    }
    #undef STAGE

    // Combine the two K-halves: waves kh=1 dump partials into LDS (reuse
    // xsf), waves kh=0 add them. Lane-major f32x4 = conflict-free.
    f32x4* __restrict__ pbuf = (f32x4*)xsf;     // 6*256*16B = 24.6 KB
    if (kh) {
        #pragma unroll
        for (int mt = 0; mt < 2; mt++)
            #pragma unroll
            for (int nt = 0; nt < 3; nt++)
                pbuf[(mt * 3 + nt) * 256 + wc * 64 + lane] = acc[mt][nt];
    }
    __syncthreads();
    if (kh) return;
    #pragma unroll
    for (int mt = 0; mt < 2; mt++)
        #pragma unroll
        for (int nt = 0; nt < 3; nt++)
            acc[mt][nt] += pbuf[(mt * 3 + nt) * 256 + wc * 64 + lane];

    // Epilogue (waves 0-3; wc owns cols [wc*48, wc*48+48))
    const int bidx = row0 >> 11;
    #pragma unroll
    for (int nt = 0; nt < 3; nt++) {
        const int n = wc * 48 + nt * 16 + l15;
        const int p = n >> 6;            // uniform per (wc,nt)
        const int h = n & 63;
        if (p < 2) {                     // q or k: RoPE
            _Float16* __restrict__ outb = (p == 0) ? qh : kh_out;
            const float invf = __expf(-0.2878231366242557f * (float)(h >> 1));
            #pragma unroll
            for (int mt = 0; mt < 2; mt++) {
                #pragma unroll
                for (int r = 0; r < 4; r++) {
                    int   row = row0 + mt * 16 + quad * 4 + r;
                    float val = acc[mt][nt][r];
                    float partner = __shfl_xor(val, 1, 64);
                    float ang = (float)(row & (Tn - 1)) * invf;
                    float sv, cv;
                    __sincosf(ang, &sv, &cv);
                    float res = (h & 1) ? fmaf(val, cv,  partner * sv)
                                        : fmaf(val, cv, -partner * sv);
                    if (p == 0) res *= 0.125f;
                    float resn = __shfl_xor(res, 1, 64);
                    if (!(l15 & 1)) {
                        f16x2 pk = { (_Float16)res, (_Float16)resn };
                        *(f16x2*)&outb[(size_t)row * Hn + h] = pk;
                    }
                }
            }
        } else {                         // v: store transposed vT[b][h][t]
            #pragma unroll
            for (int mt = 0; mt < 2; mt++) {
                int t = (row0 & (Tn - 1)) + mt * 16 + quad * 4;
                f16x4 pv = { (_Float16)acc[mt][nt][0], (_Float16)acc[mt][nt][1],
                             (_Float16)acc[mt][nt][2], (_Float16)acc[mt][nt][3] };
                *(f16x4*)&vT[((size_t)bidx * Hn + h) * Tn + t] = pv;
            }
        }
    }
}

// ---------------------------------------------------------------------------
// attn: barrier-free flash loop (EXACT round-2 version, the best measured).
// QT=16, STL=64, 256 thr = 4 waves; each wave processes every 4th s-tile
// with its own online-softmax state; one barrier + LDS merge at the end.
// K and vT B-frags read directly from global (L2-resident, XCD-affine via
// b = blk&7). qt permuted so each CU's resident blocks have constant work.
// ---------------------------------------------------------------------------
#define PSP 72

__global__ __launch_bounds__(256, 4) void attn_kernel(
    const _Float16* __restrict__ qh, const _Float16* __restrict__ kh,
    const _Float16* __restrict__ vT, float* __restrict__ out)
{
    __shared__ _Float16 ps[4][16 * PSP];     // wave-private P transpose
    __shared__ float ocomb[4][16][65];
    __shared__ float mlcomb[4][2][16];       // [wave][m|l][row]

    const int blk = blockIdx.x;
    const int b   = blk & 7;                 // batch == XCD affinity
    const int j   = blk >> 3;                // 0..127
    const int jm  = j & 31, g = j >> 5;      // complement permutation:
    const int qt  = (g == 0) ? (127 - jm)    // per-CU resident set sums const
                  : (g == 1) ? (64 + jm)
                  : (g == 2) ? (63 - jm) : jm;
    const int t0  = qt * 16;
    const int tid = threadIdx.x;
    const int w = tid >> 6, lane = tid & 63;
    const int quad = lane >> 4, l15 = lane & 15;

    const _Float16* __restrict__ qb = qh + (size_t)b * Tn * Hn;
    const _Float16* __restrict__ kb = kh + (size_t)b * Tn * Hn;
    const _Float16* __restrict__ vb = vT + (size_t)b * Hn * Tn;

    // Q A-frags: held in registers for the whole loop
    const f16x8 aq0 = *(const f16x8*)&qb[(size_t)(t0 + l15) * Hn +      quad * 8];
    const f16x8 aq1 = *(const f16x8*)&qb[(size_t)(t0 + l15) * Hn + 32 + quad * 8];

    float m_run[4], l_run[4];
    f32x4 oacc[4] = {};
    #pragma unroll
    for (int r = 0; r < 4; r++) { m_run[r] = -1e30f; l_run[r] = 0.0f; }

    const int nst = (t0 + 16 + 63) >> 6;
    for (int jt = w; jt < nst; jt += 4) {
        const int s0 = jt * 64;

        // K B-frags direct from global (16 rows x 64B per load instr)
        f16x8 kf[4][2];
        #pragma unroll
        for (int nt = 0; nt < 4; nt++) {
            const _Float16* kp = &kb[(size_t)(s0 + nt * 16 + l15) * Hn + quad * 8];
            kf[nt][0] = *(const f16x8*)kp;
            kf[nt][1] = *(const f16x8*)(kp + 32);
        }
        f32x4 sacc[4];
        #pragma unroll
        for (int nt = 0; nt < 4; nt++) {
            f32x4 z = {};
            z = MFMA16(aq0, kf[nt][0], z);
            z = MFMA16(aq1, kf[nt][1], z);
            sacc[nt] = z;
        }

        // vT B-frags: issue before softmax (independent), consumed by PV
        f16x8 vf[2][4];
        #pragma unroll
        for (int sc = 0; sc < 2; sc++)
            #pragma unroll
            for (int ht = 0; ht < 4; ht++)
                vf[sc][ht] = *(const f16x8*)&vb[(size_t)(ht * 16 + l15) * Tn
                                                + s0 + sc * 32 + quad * 8];

        if (jt == nst - 1) {             // causal mask: only diagonal tile
            #pragma unroll
            for (int nt = 0; nt < 4; nt++)
                #pragma unroll
                for (int r = 0; r < 4; r++) {
                    int scol = s0 + nt * 16 + l15;
                    int trow = t0 + quad * 4 + r;
                    if (scol > trow) sacc[nt][r] = -1e30f;
                }
        }

        // online softmax (rows = quad*4+r; reduce over the 16 l15 lanes)
        float pr[4][4];
        #pragma unroll
        for (int r = 0; r < 4; r++) {
            float mx = fmaxf(fmaxf(sacc[0][r], sacc[1][r]),
                             fmaxf(sacc[2][r], sacc[3][r]));
            #pragma unroll
            for (int off = 1; off < 16; off <<= 1)
                mx = fmaxf(mx, __shfl_xor(mx, off, 64));
            float mnew  = fmaxf(m_run[r], mx);
            float alpha = __expf(m_run[r] - mnew);
            m_run[r] = mnew;
            float rs = 0.0f;
            #pragma unroll
            for (int nt = 0; nt < 4; nt++) {
                float pv = __expf(sacc[nt][r] - mnew);
                pr[nt][r] = pv; rs += pv;
            }
            #pragma unroll
            for (int off = 1; off < 16; off <<= 1)
                rs += __shfl_xor(rs, off, 64);
            l_run[r] = fmaf(l_run[r], alpha, rs);
            #pragma unroll
            for (int ht = 0; ht < 4; ht++)
                oacc[ht][r] = oacc[ht][r] * alpha;
        }

        // P -> ps (wave-private; same-wave RAW, no barrier)
        #pragma unroll
        for (int nt = 0; nt < 4; nt++)
            #pragma unroll
            for (int r = 0; r < 4; r++) {
                float pv = pr[nt][r];
                float pn = __shfl_xor(pv, 1, 64);
                if (!(l15 & 1)) {
                    f16x2 pk = { (_Float16)pv, (_Float16)pn };
                    *(f16x2*)&ps[w][(quad * 4 + r) * PSP + nt * 16 + l15] = pk;
                }
            }

        // O += P V  (8 MFMA, B-frags already in registers)
        #pragma unroll
        for (int sc = 0; sc < 2; sc++) {
            f16x8 ap = *(const f16x8*)&ps[w][l15 * PSP + sc * 32 + quad * 8];
            #pragma unroll
            for (int ht = 0; ht < 4; ht++)
                oacc[ht] = MFMA16(ap, vf[sc][ht], oacc[ht]);
        }
    }

    // Write partials, barrier, merge the four waves' online-softmax states.
    #pragma unroll
    for (int r = 0; r < 4; r++) {
        #pragma unroll
        for (int ht = 0; ht < 4; ht++)
            ocomb[w][quad * 4 + r][ht * 16 + l15] = oacc[ht][r];
        if (l15 == 0) {
            mlcomb[w][0][quad * 4 + r] = m_run[r];
            mlcomb[w][1][quad * 4 + r] = l_run[r];
        }
    }
    __syncthreads();

    // wave w finalizes rows [w*4, w*4+4); 64 lanes = 64 h (coalesced)
    #pragma unroll
    for (int rp = 0; rp < 4; rp++) {
        int row = w * 4 + rp;
        float m0 = mlcomb[0][0][row], m1 = mlcomb[1][0][row];
        float m2 = mlcomb[2][0][row], m3 = mlcomb[3][0][row];
        float mm = fmaxf(fmaxf(m0, m1), fmaxf(m2, m3));
        float a0 = __expf(m0 - mm), a1 = __expf(m1 - mm);
        float a2 = __expf(m2 - mm), a3 = __expf(m3 - mm);
        float ll = mlcomb[0][1][row] * a0 + mlcomb[1][1][row] * a1
                 + mlcomb[2][1][row] * a2 + mlcomb[3][1][row] * a3;
        float ov = (ocomb[0][row][lane] * a0 + ocomb[1][row][lane] * a1
                  + ocomb[2][row][lane] * a2 + ocomb[3][row][lane] * a3) / ll;
        out[((size_t)b * Tn + t0 + row) * Hn + lane] = ov;
    }
}

extern "C" void kernel_launch(void* const* d_in, const int* in_sizes, int n_in,
                              void* d_out, int out_size, void* d_ws, size_t ws_size,
                              hipStream_t stream) {
    const float* x  = (const float*)d_in[0];
    const float* Wq = (const float*)d_in[1];
    const float* Wk = (const float*)d_in[2];
    const float* Wv = (const float*)d_in[3];

    const size_t qkvN = (size_t)BTn * Hn;
    _Float16* qh = (_Float16*)d_ws;
    _Float16* kh = qh + qkvN;
    _Float16* vT = kh + qkvN;                     // [8][64][2048] transposed
    _Float16* Wt = vT + qkvN;                     // [192][1024] f16

    prep_w_kernel<<<48, 256, 0, stream>>>(Wq, Wk, Wv, Wt);
    proj_kernel<<<BTn / 32, 512, 0, stream>>>(x, Wt, qh, kh, vT);
    attn_kernel<<<1024, 256, 0, stream>>>(qh, kh, vT, (float*)d_out);
}